// Round 10
// baseline (478.625 us; speedup 1.0000x reference)
//
#include <hip/hip_runtime.h>

#define BT 16384
#define NF 39
#define FD 26000

typedef unsigned short u16;
typedef unsigned int u32;
typedef short bf16x8 __attribute__((ext_vector_type(8)));
typedef float f32x4 __attribute__((ext_vector_type(4)));

__device__ __forceinline__ float bf2f(u16 h) {
  union { u32 u; float f; } v; v.u = ((u32)h) << 16; return v.f;
}
__device__ __forceinline__ u16 f2bf(float f) {
  union { float f; u32 u; } v; v.f = f;
  u32 r = v.u + 0x7fffu + ((v.u >> 16) & 1u);
  return (u16)(r >> 16);
}
// async global->LDS, 16B/lane; LDS dest = wave-uniform base + lane*16.
__device__ __forceinline__ void gld16(const u16* g, u16* l) {
  __builtin_amdgcn_global_load_lds(
      (const __attribute__((address_space(1))) void*)g,
      (__attribute__((address_space(3))) void*)l, 16, 0, 0);
}

// ---------------------------------------------------------------------------
// prep: z=0..2 transpose+cast W1/W2/W3 (f32 [K][400] -> bf16 [400+][Kpad],
// K-pad zero);  z=3 cast Wt -> bf16 (row-major, unchanged layout).
// ---------------------------------------------------------------------------
__global__ __launch_bounds__(256) void k_prep(
    const float* __restrict__ W1, u16* __restrict__ W1T,
    const float* __restrict__ W2, u16* __restrict__ W2T,
    const float* __restrict__ W3, u16* __restrict__ W3T,
    const float* __restrict__ Wt, u16* __restrict__ Wtb)
{
  int z = blockIdx.z;
  if (z == 3) {
    int idx = (blockIdx.y * 14 + blockIdx.x) * 256 + threadIdx.x;
    if (idx < NF * 4096) Wtb[idx] = f2bf(Wt[idx]);
    return;
  }
  const float* in = (z == 0) ? W1 : (z == 1) ? W2 : W3;
  u16* outp = (z == 0) ? W1T : (z == 1) ? W2T : W3T;
  int K = (z == 0) ? 2496 : 400;
  int Kpad = (z == 0) ? 2496 : 448;
  int r0 = blockIdx.y * 32, c0 = blockIdx.x * 32;
  if (r0 >= Kpad) return;
  __shared__ u16 t[32][33];
  int tx = threadIdx.x & 31, ty = threadIdx.x >> 5;
  for (int i = ty; i < 32; i += 8) {
    int r = r0 + i, c = c0 + tx;
    t[i][tx] = (r < K && c < 400) ? f2bf(in[(long)r * 400 + c]) : (u16)0;
  }
  __syncthreads();
  int r = r0 + tx;
  if (r < Kpad)
    for (int i = ty; i < 32; i += 8)
      outp[(long)(c0 + i) * Kpad + r] = t[tx][i];   // rows >=400 are scratch-pad
}

// ---------------------------------------------------------------------------
// k_embed (round-9 base + gather prefetch DISTANCE 2): gather+gate -> h0
// (bf16) + per-field 64x64 linear (MFMA) for FM + first-order term.
// 512 blocks x 32 rows; double-buffered LDS, 1 barrier/field.
// emb table (260MB) > L3, so gathers are ~900cy HBM misses; distance-1
// prefetch only covered ~300cy of MFMA+VALU body.  Two named register sets
// (eA/eB, manual 2-unroll -> compile-time indices) give each gather a full
// iteration + barrier of coverage.  Wt staging stays distance-1 (L2-hot).
// ---------------------------------------------------------------------------
__global__ __launch_bounds__(256) void k_embed(
    const int* __restrict__ x, const float* __restrict__ emb,
    const float* __restrict__ lin_table, const float* __restrict__ lin_bias,
    const float* __restrict__ sparse_var, const u16* __restrict__ Wtb,
    const float* __restrict__ bt, u16* __restrict__ h0, float* __restrict__ base)
{
  __shared__ u16                s_x[32 * NF];        // 2496 B
  __shared__ float              s_sv[NF * 64];       // 9984 B
  __shared__ float              s_bt[NF * 64];       // 9984 B
  __shared__ __align__(16) u16  s_emb[2][32 * 72];   // 9216 B (stride 72)
  __shared__ __align__(16) u16  s_wt[2][64 * 64];    // 16384 B (chunk-swizzled)
  __shared__ float              s_fm[64];            // 256 B
  __shared__ float              s_lin[32];           // 128 B  -> 48448 B

  const int tid = threadIdx.x;
  const int b0 = blockIdx.x * 32;

  for (int i = tid; i < 32 * NF; i += 256) s_x[i] = (u16)x[b0 * NF + i];
  for (int i = tid; i < NF * 64; i += 256) {
    float v = sparse_var[i];
    float s = 1.0f / (1.0f + __expf(-15.0f * v));
    s_sv[i] = (s > 0.001f) ? s : 0.0f;
    s_bt[i] = bt[i];
  }
  __syncthreads();

  const int wave = tid >> 6, lane = tid & 63;
  const int quad = lane >> 4, c16 = lane & 15;
  const int mt = wave & 1, nh = wave >> 1;
  const int g_row = tid >> 3, g_c8 = (tid & 7) * 8;
  // Wt staging: lane -> (row_rel = lane>>3, phys chunk = lane&7); fetch
  // logical chunk (lane&7)^row_rel so phys p at row r holds logical p^(r&7).
  const int wrow = lane >> 3;
  const int wchk = (lane & 7) ^ wrow;

  float q[4] = {0.f, 0.f, 0.f, 0.f};
  float accS[2][4] = {{0.f,0.f,0.f,0.f},{0.f,0.f,0.f,0.f}};

  // ---- prologue: stage Wt[0]; gather+pack field 0; issue gather field 1
  #pragma unroll
  for (int i = 0; i < 2; ++i) {
    int ii = wave * 2 + i;
    gld16(Wtb + (ii * 8 + wrow) * 64 + wchk * 8, &s_wt[0][ii * 512]);
  }
  {
    long gi = (long)((int)s_x[g_row * NF + 0]);
    float4 e0 = *(const float4*)&emb[gi * 64 + g_c8];
    float4 e1 = *(const float4*)&emb[gi * 64 + g_c8 + 4];
    union { uint4 v; u16 h[8]; } p;
    p.h[0] = f2bf(e0.x * s_sv[g_c8 + 0]);
    p.h[1] = f2bf(e0.y * s_sv[g_c8 + 1]);
    p.h[2] = f2bf(e0.z * s_sv[g_c8 + 2]);
    p.h[3] = f2bf(e0.w * s_sv[g_c8 + 3]);
    p.h[4] = f2bf(e1.x * s_sv[g_c8 + 4]);
    p.h[5] = f2bf(e1.y * s_sv[g_c8 + 5]);
    p.h[6] = f2bf(e1.z * s_sv[g_c8 + 6]);
    p.h[7] = f2bf(e1.w * s_sv[g_c8 + 7]);
    *(uint4*)&s_emb[0][g_row * 72 + g_c8] = p.v;
    *(uint4*)&h0[(long)(b0 + g_row) * 2496 + g_c8] = p.v;
  }
  float4 eA0, eA1, eB0, eB1;
  {
    long gi = (long)((int)s_x[g_row * NF + 1] + 1 * FD);
    eA0 = *(const float4*)&emb[gi * 64 + g_c8];
    eA1 = *(const float4*)&emb[gi * 64 + g_c8 + 4];
  }
  __syncthreads();

  // body(f): consumes IN (= gather of f+1), issues OUT (= gather of f+2)
#define EMB_ITER(f, IN0, IN1, OUT0, OUT1)                                     \
  {                                                                           \
    const int cur = (f) & 1, nxt = cur ^ 1;                                   \
    const bool more1 = (f) + 1 < NF;                                          \
    const bool more2 = (f) + 2 < NF;                                          \
    if (more1) {                                                              \
      _Pragma("unroll")                                                       \
      for (int i = 0; i < 2; ++i) {                                           \
        int ii = wave * 2 + i;                                                \
        gld16(Wtb + ((f) + 1) * 4096 + (ii * 8 + wrow) * 64 + wchk * 8,       \
              &s_wt[nxt][ii * 512]);                                          \
      }                                                                       \
    }                                                                         \
    if (more2) {                                                              \
      long gi = (long)((int)s_x[g_row * NF + (f) + 2] + ((f) + 2) * FD);      \
      OUT0 = *(const float4*)&emb[gi * 64 + g_c8];                            \
      OUT1 = *(const float4*)&emb[gi * 64 + g_c8 + 4];                        \
    }                                                                         \
    bf16x8 a0 = *(const bf16x8*)&s_emb[cur][(mt * 16 + c16) * 72 + quad * 8]; \
    bf16x8 a1 = *(const bf16x8*)&s_emb[cur][(mt * 16 + c16) * 72 + 32 + quad * 8]; \
    _Pragma("unroll")                                                         \
    for (int j = 0; j < 2; ++j) {                                             \
      int row = (nh * 2 + j) * 16 + c16;                                      \
      int pc0 = quad ^ (row & 7);                                             \
      int pc1 = (quad + 4) ^ (row & 7);                                       \
      bf16x8 bb0 = *(const bf16x8*)&s_wt[cur][row * 64 + pc0 * 8];            \
      bf16x8 bb1 = *(const bf16x8*)&s_wt[cur][row * 64 + pc1 * 8];            \
      f32x4 acc = {0.f, 0.f, 0.f, 0.f};                                       \
      acc = __builtin_amdgcn_mfma_f32_16x16x32_bf16(a0, bb0, acc, 0, 0, 0);   \
      acc = __builtin_amdgcn_mfma_f32_16x16x32_bf16(a1, bb1, acc, 0, 0, 0);   \
      float btv = s_bt[(f) * 64 + row];                                       \
      _Pragma("unroll")                                                       \
      for (int r = 0; r < 4; ++r) {                                           \
        float t = acc[r] + btv;                                               \
        accS[j][r] += t;                                                      \
        q[r] += t * t;                                                        \
      }                                                                       \
    }                                                                         \
    if (more1) {                                                              \
      union { uint4 v; u16 h[8]; } p;                                         \
      const float* sv = &s_sv[((f) + 1) * 64 + g_c8];                         \
      p.h[0] = f2bf(IN0.x * sv[0]);                                           \
      p.h[1] = f2bf(IN0.y * sv[1]);                                           \
      p.h[2] = f2bf(IN0.z * sv[2]);                                           \
      p.h[3] = f2bf(IN0.w * sv[3]);                                           \
      p.h[4] = f2bf(IN1.x * sv[4]);                                           \
      p.h[5] = f2bf(IN1.y * sv[5]);                                           \
      p.h[6] = f2bf(IN1.z * sv[6]);                                           \
      p.h[7] = f2bf(IN1.w * sv[7]);                                           \
      *(uint4*)&s_emb[nxt][g_row * 72 + g_c8] = p.v;                          \
      *(uint4*)&h0[(long)(b0 + g_row) * 2496 + ((f) + 1) * 64 + g_c8] = p.v;  \
    }                                                                         \
    __syncthreads();                                                          \
  }

  for (int f = 0; f < NF; f += 2) {
    EMB_ITER(f, eA0, eA1, eB0, eB1);
    if (f + 1 < NF) EMB_ITER(f + 1, eB0, eB1, eA0, eA1);
  }
#undef EMB_ITER

  // FM: per row r, (S_half0)^2+(S_half1)^2 - q, reduced over the 16 col-lanes
  #pragma unroll
  for (int r = 0; r < 4; ++r) {
    float v = accS[0][r] * accS[0][r] + accS[1][r] * accS[1][r] - q[r];
    v += __shfl_xor(v, 1, 64);
    v += __shfl_xor(v, 2, 64);
    v += __shfl_xor(v, 4, 64);
    v += __shfl_xor(v, 8, 64);
    if (c16 == 0) s_fm[nh * 32 + mt * 16 + quad * 4 + r] = v;
  }
  // first-order term: 8 threads per row, fields strided by 8
  {
    int row = tid >> 3, fi = tid & 7;
    float lv = 0.f;
    for (int f = fi; f < NF; f += 8)
      lv += lin_table[(int)s_x[row * NF + f] + f * FD];
    lv += __shfl_xor(lv, 1, 64);
    lv += __shfl_xor(lv, 2, 64);
    lv += __shfl_xor(lv, 4, 64);
    if (fi == 0) s_lin[row] = lv;
  }
  __syncthreads();
  if (tid < 32)
    base[b0 + tid] = s_lin[tid] + lin_bias[0]
                   + 0.5f * (s_fm[tid] + s_fm[32 + tid]);
}

// ---------------------------------------------------------------------------
// MLP GEMM, m97-style: global_load_lds(16B) staging, XOR-swizzled unpadded
// LDS, tile 128x112xBK64 (4 n-blocks), grid 512 = 2 blocks/CU exactly.
// C = relu((A@B + b)*BN_INV*g + be); cols >=400 written 0.
// ---------------------------------------------------------------------------
__global__ __launch_bounds__(256) void k_gemm(
    const u16* __restrict__ A, int lda, const u16* __restrict__ Bt, int ldb,
    int kit, const float* __restrict__ bias, const float* __restrict__ g,
    const float* __restrict__ be, u16* __restrict__ C, int ldc)
{
  __shared__ __align__(16) u16 sA[128 * 64];  // 16 KB, chunk-swizzled
  __shared__ __align__(16) u16 sB[112 * 64];  // 14 KB

  const int tid = threadIdx.x;
  // 512 blocks = 8 xcd * 16 m * 4 n : co-locate an A-panel's 4 n-blocks per XCD
  int bid = blockIdx.x;
  int xcd = bid & 7;
  int j = bid >> 3;
  const int m0 = (xcd * 16 + (j >> 2)) * 128;
  const int n0 = (j & 3) * 112;

  const int wave = tid >> 6, lane = tid & 63;
  const int quad = lane >> 4, c16 = lane & 15;

  const int srow = lane >> 3;
  const int sclog = (lane & 7) ^ (srow & 7);
  const u16* gA = A + (long)m0 * lda + sclog * 8;
  const u16* gB = Bt + (long)n0 * ldb + sclog * 8;

  f32x4 acc[2][7];
  #pragma unroll
  for (int mtt = 0; mtt < 2; ++mtt)
    #pragma unroll
    for (int nt = 0; nt < 7; ++nt) acc[mtt][nt] = {0.f, 0.f, 0.f, 0.f};

  for (int kk = 0; kk < kit; ++kk) {
    const int k0 = kk * 64;
    #pragma unroll
    for (int it = 0; it < 4; ++it) {
      int s = wave * 4 + it;
      gld16(gA + (long)(s * 8 + srow) * lda + k0, &sA[s * 512]);
    }
    gld16(gB + (long)(wave * 8 + srow) * ldb + k0, &sB[wave * 512]);
    gld16(gB + (long)((wave + 4) * 8 + srow) * ldb + k0, &sB[(wave + 4) * 512]);
    gld16(gB + (long)((wave + 8) * 8 + srow) * ldb + k0, &sB[(wave + 8) * 512]);
    if (wave < 2)
      gld16(gB + (long)((wave + 12) * 8 + srow) * ldb + k0, &sB[(wave + 12) * 512]);
    __syncthreads();

    #pragma unroll
    for (int ks = 0; ks < 2; ++ks) {
      const int co = ((ks * 4 + quad) ^ (c16 & 7)) * 8;
      bf16x8 a0 = *(const bf16x8*)&sA[(wave * 32 + c16) * 64 + co];
      bf16x8 a1 = *(const bf16x8*)&sA[(wave * 32 + 16 + c16) * 64 + co];
      #pragma unroll
      for (int nt = 0; nt < 7; ++nt) {
        bf16x8 b = *(const bf16x8*)&sB[(nt * 16 + c16) * 64 + co];
        acc[0][nt] = __builtin_amdgcn_mfma_f32_16x16x32_bf16(a0, b, acc[0][nt], 0, 0, 0);
        acc[1][nt] = __builtin_amdgcn_mfma_f32_16x16x32_bf16(a1, b, acc[1][nt], 0, 0, 0);
      }
    }
    __syncthreads();
  }

  const float BN_INV = 0.9999950000374997f;
  #pragma unroll
  for (int nt = 0; nt < 7; ++nt) {
    int col = n0 + nt * 16 + c16;
    if (col < 400) {
      float bb = bias[col];
      float sc = BN_INV * g[col];
      float bv = be[col];
      #pragma unroll
      for (int mtt = 0; mtt < 2; ++mtt) {
        #pragma unroll
        for (int r = 0; r < 4; ++r) {
          int row = m0 + wave * 32 + mtt * 16 + quad * 4 + r;
          float y = (acc[mtt][nt][r] + bb) * sc + bv;
          y = fmaxf(y, 0.f);
          C[(long)row * ldc + col] = f2bf(y);
        }
      }
    } else if (col < ldc) {
      #pragma unroll
      for (int mtt = 0; mtt < 2; ++mtt)
        #pragma unroll
        for (int r = 0; r < 4; ++r)
          C[(long)(m0 + wave * 32 + mtt * 16 + quad * 4 + r) * ldc + col] = 0;
    }
  }
}

// ---------------------------------------------------------------------------
// Final: out[b] = sigmoid(base[b] + h3[b,:].Wout + bout). One wave per row.
// ---------------------------------------------------------------------------
__global__ __launch_bounds__(256) void k_final(
    const u16* __restrict__ h3, const float* __restrict__ Wout,
    const float* __restrict__ bout, const float* __restrict__ base,
    float* __restrict__ out)
{
  int wave = threadIdx.x >> 6, lane = threadIdx.x & 63;
  int b = blockIdx.x * 4 + wave;
  float s = 0.f;
  for (int jj = lane; jj < 400; jj += 64)
    s += bf2f(h3[(long)b * 448 + jj]) * Wout[jj];
  #pragma unroll
  for (int m = 32; m >= 1; m >>= 1) s += __shfl_xor(s, m, 64);
  if (lane == 0) {
    float z = s + base[b] + bout[0];
    out[b] = 1.0f / (1.0f + __expf(-z));
  }
}

extern "C" void kernel_launch(void* const* d_in, const int* in_sizes, int n_in,
                              void* d_out, int out_size, void* d_ws, size_t ws_size,
                              hipStream_t stream)
{
  const int*   x         = (const int*)d_in[0];
  const float* emb       = (const float*)d_in[1];
  const float* lin_table = (const float*)d_in[2];
  const float* lin_bias  = (const float*)d_in[3];
  const float* svar      = (const float*)d_in[4];
  const float* Wt        = (const float*)d_in[5];
  const float* bt        = (const float*)d_in[6];
  const float* W1  = (const float*)d_in[7];
  const float* b1  = (const float*)d_in[8];
  const float* g1  = (const float*)d_in[9];
  const float* be1 = (const float*)d_in[10];
  const float* W2  = (const float*)d_in[11];
  const float* b2  = (const float*)d_in[12];
  const float* g2  = (const float*)d_in[13];
  const float* be2 = (const float*)d_in[14];
  const float* W3  = (const float*)d_in[15];
  const float* b3  = (const float*)d_in[16];
  const float* g3  = (const float*)d_in[17];
  const float* be3 = (const float*)d_in[18];
  const float* Wo  = (const float*)d_in[19];
  const float* bo  = (const float*)d_in[20];

  char* ws = (char*)d_ws;
  size_t off = 0;
  u16* h0 = (u16*)(ws + off);     off += (size_t)BT * 2496 * 2;   // 81.8 MB
  u16* h1 = (u16*)(ws + off);     off += (size_t)BT * 448 * 2;
  u16* h2 = (u16*)(ws + off);     off += (size_t)BT * 448 * 2;
  u16* h3 = (u16*)(ws + off);     off += (size_t)BT * 448 * 2;
  float* base = (float*)(ws + off); off += (size_t)BT * 4;
  u16* W1T = (u16*)(ws + off);    off += (size_t)448 * 2496 * 2;
  u16* W2T = (u16*)(ws + off);    off += (size_t)448 * 448 * 2;
  u16* W3T = (u16*)(ws + off);    off += (size_t)448 * 448 * 2;
  u16* Wtb = (u16*)(ws + off);    off += (size_t)NF * 4096 * 2;
  (void)ws_size; (void)in_sizes; (void)n_in; (void)out_size;

  k_prep<<<dim3(14, 78, 4), 256, 0, stream>>>(W1, W1T, W2, W2T, W3, W3T, Wt, Wtb);
  k_embed<<<512, 256, 0, stream>>>(x, emb, lin_table, lin_bias, svar, Wtb, bt,
                                   h0, base);
  k_gemm<<<512, 256, 0, stream>>>(h0, 2496, W1T, 2496, 39, b1, g1, be1, h1, 448);
  k_gemm<<<512, 256, 0, stream>>>(h1, 448, W2T, 448, 7, b2, g2, be2, h2, 448);
  k_gemm<<<512, 256, 0, stream>>>(h2, 448, W3T, 448, 7, b3, g3, be3, h3, 448);
  k_final<<<4096, 256, 0, stream>>>(h3, Wo, bo, base, (float*)d_out);
}

// Round 11
// 476.397 us; speedup vs baseline: 1.0047x; 1.0047x over previous
//
#include <hip/hip_runtime.h>

#define BT 16384
#define NF 39
#define FD 26000

typedef unsigned short u16;
typedef unsigned int u32;
typedef short bf16x8 __attribute__((ext_vector_type(8)));
typedef float f32x4 __attribute__((ext_vector_type(4)));

__device__ __forceinline__ float bf2f(u16 h) {
  union { u32 u; float f; } v; v.u = ((u32)h) << 16; return v.f;
}
__device__ __forceinline__ u16 f2bf(float f) {
  union { float f; u32 u; } v; v.f = f;
  u32 r = v.u + 0x7fffu + ((v.u >> 16) & 1u);
  return (u16)(r >> 16);
}
// async global->LDS, 16B/lane; LDS dest = wave-uniform base + lane*16.
__device__ __forceinline__ void gld16(const u16* g, u16* l) {
  __builtin_amdgcn_global_load_lds(
      (const __attribute__((address_space(1))) void*)g,
      (__attribute__((address_space(3))) void*)l, 16, 0, 0);
}

// ---------------------------------------------------------------------------
// prep: z=0..2 transpose+cast W1/W2/W3 (f32 [K][400] -> bf16 [400+][Kpad],
// K-pad zero);  z=3 cast Wt -> bf16 (row-major, unchanged layout).
// ---------------------------------------------------------------------------
__global__ __launch_bounds__(256) void k_prep(
    const float* __restrict__ W1, u16* __restrict__ W1T,
    const float* __restrict__ W2, u16* __restrict__ W2T,
    const float* __restrict__ W3, u16* __restrict__ W3T,
    const float* __restrict__ Wt, u16* __restrict__ Wtb)
{
  int z = blockIdx.z;
  if (z == 3) {
    int idx = (blockIdx.y * 14 + blockIdx.x) * 256 + threadIdx.x;
    if (idx < NF * 4096) Wtb[idx] = f2bf(Wt[idx]);
    return;
  }
  const float* in = (z == 0) ? W1 : (z == 1) ? W2 : W3;
  u16* outp = (z == 0) ? W1T : (z == 1) ? W2T : W3T;
  int K = (z == 0) ? 2496 : 400;
  int Kpad = (z == 0) ? 2496 : 448;
  int r0 = blockIdx.y * 32, c0 = blockIdx.x * 32;
  if (r0 >= Kpad) return;
  __shared__ u16 t[32][33];
  int tx = threadIdx.x & 31, ty = threadIdx.x >> 5;
  for (int i = ty; i < 32; i += 8) {
    int r = r0 + i, c = c0 + tx;
    t[i][tx] = (r < K && c < 400) ? f2bf(in[(long)r * 400 + c]) : (u16)0;
  }
  __syncthreads();
  int r = r0 + tx;
  if (r < Kpad)
    for (int i = ty; i < 32; i += 8)
      outp[(long)(c0 + i) * Kpad + r] = t[tx][i];   // rows >=400 are scratch-pad
}

// ---------------------------------------------------------------------------
// k_embed (round-9 base + PAIRED FIELDS): gather+gate -> h0 (bf16) +
// per-field 64x64 linear (MFMA) for FM + first-order term.
// 512 blocks x 32 rows.  Mechanism finding (r10): each __syncthreads emits a
// vmcnt(0) drain of ALL outstanding VMEM (Wt stages + gathers + h0 stores) —
// prefetch depth cannot cross it.  So amortize it: process TWO fields per
// barrier (s_wt[2][2][4K], s_emb[2][2][2.3K] -> 74KB LDS, 2 blk/CU which the
// 512-block grid already caps).  Barriers 39 -> 20; per-barrier work doubles.
// Field order inside a pair is sequential -> FM accum order & h0 bit-identical.
// ---------------------------------------------------------------------------
__global__ __launch_bounds__(256) void k_embed(
    const int* __restrict__ x, const float* __restrict__ emb,
    const float* __restrict__ lin_table, const float* __restrict__ lin_bias,
    const float* __restrict__ sparse_var, const u16* __restrict__ Wtb,
    const float* __restrict__ bt, u16* __restrict__ h0, float* __restrict__ base)
{
  __shared__ u16                s_x[32 * NF];           //  2496 B
  __shared__ float              s_sv[NF * 64];          //  9984 B
  __shared__ float              s_bt[NF * 64];          //  9984 B
  __shared__ __align__(16) u16  s_emb[2][2][32 * 72];   // 18432 B
  __shared__ __align__(16) u16  s_wt[2][2][64 * 64];    // 32768 B
  __shared__ float              s_fm[64];               //   256 B
  __shared__ float              s_lin[32];              //   128 B -> 74048 B

  const int tid = threadIdx.x;
  const int b0 = blockIdx.x * 32;

  for (int i = tid; i < 32 * NF; i += 256) s_x[i] = (u16)x[b0 * NF + i];
  for (int i = tid; i < NF * 64; i += 256) {
    float v = sparse_var[i];
    float s = 1.0f / (1.0f + __expf(-15.0f * v));
    s_sv[i] = (s > 0.001f) ? s : 0.0f;
    s_bt[i] = bt[i];
  }
  __syncthreads();

  const int wave = tid >> 6, lane = tid & 63;
  const int quad = lane >> 4, c16 = lane & 15;
  const int mt = wave & 1, nh = wave >> 1;
  const int g_row = tid >> 3, g_c8 = (tid & 7) * 8;
  // Wt staging: lane -> (row_rel = lane>>3, phys chunk = lane&7); fetch
  // logical chunk (lane&7)^row_rel so phys p at row r holds logical p^(r&7).
  const int wrow = lane >> 3;
  const int wchk = (lane & 7) ^ wrow;

  float q[4] = {0.f, 0.f, 0.f, 0.f};
  float accS[2][4] = {{0.f,0.f,0.f,0.f},{0.f,0.f,0.f,0.f}};

  // pack helper: gate e0/e1 with s_sv[f], write s_emb[buf][ff] + h0[f]
#define EMB_PACK(buf, ff, f, E0, E1)                                          \
  {                                                                           \
    const float* sv = &s_sv[(f) * 64 + g_c8];                                 \
    union { uint4 v; u16 h[8]; } p;                                           \
    p.h[0] = f2bf(E0.x * sv[0]);                                              \
    p.h[1] = f2bf(E0.y * sv[1]);                                              \
    p.h[2] = f2bf(E0.z * sv[2]);                                              \
    p.h[3] = f2bf(E0.w * sv[3]);                                              \
    p.h[4] = f2bf(E1.x * sv[4]);                                              \
    p.h[5] = f2bf(E1.y * sv[5]);                                              \
    p.h[6] = f2bf(E1.z * sv[6]);                                              \
    p.h[7] = f2bf(E1.w * sv[7]);                                              \
    *(uint4*)&s_emb[buf][ff][g_row * 72 + g_c8] = p.v;                        \
    *(uint4*)&h0[(long)(b0 + g_row) * 2496 + (f) * 64 + g_c8] = p.v;          \
  }

  // ---- prologue: stage Wt fields 0,1; gather+pack fields 0,1
  #pragma unroll
  for (int i = 0; i < 2; ++i) {
    int ii = wave * 2 + i;
    gld16(Wtb + (ii * 8 + wrow) * 64 + wchk * 8, &s_wt[0][0][ii * 512]);
    gld16(Wtb + 4096 + (ii * 8 + wrow) * 64 + wchk * 8, &s_wt[0][1][ii * 512]);
  }
  {
    long gi0 = (long)((int)s_x[g_row * NF + 0]);
    long gi1 = (long)((int)s_x[g_row * NF + 1] + FD);
    float4 a0 = *(const float4*)&emb[gi0 * 64 + g_c8];
    float4 a1 = *(const float4*)&emb[gi0 * 64 + g_c8 + 4];
    float4 b0f = *(const float4*)&emb[gi1 * 64 + g_c8];
    float4 b1f = *(const float4*)&emb[gi1 * 64 + g_c8 + 4];
    EMB_PACK(0, 0, 0, a0, a1);
    EMB_PACK(0, 1, 1, b0f, b1f);
  }
  __syncthreads();

  // ---- main loop: 20 pair-iterations, one barrier each
  for (int p = 0; p < 20; ++p) {
    const int cur = p & 1, nxt = cur ^ 1;
    const int f0 = 2 * p;              // always < 39
    const int f1 = f0 + 1;             // < 39 except p == 19
    const bool hasf1 = f1 < NF;
    const int pf0 = f0 + 2, pf1 = f1 + 2;
    const bool pre0 = pf0 < NF, pre1 = pf1 < NF;

    // stage Wt for the next pair
    if (pre0) {
      #pragma unroll
      for (int i = 0; i < 2; ++i) {
        int ii = wave * 2 + i;
        gld16(Wtb + pf0 * 4096 + (ii * 8 + wrow) * 64 + wchk * 8,
              &s_wt[nxt][0][ii * 512]);
      }
    }
    if (pre1) {
      #pragma unroll
      for (int i = 0; i < 2; ++i) {
        int ii = wave * 2 + i;
        gld16(Wtb + pf1 * 4096 + (ii * 8 + wrow) * 64 + wchk * 8,
              &s_wt[nxt][1][ii * 512]);
      }
    }

    // gather prefetch for the next pair (consumed by the pack below)
    float4 e00, e01, e10, e11;
    if (pre0) {
      long gi = (long)((int)s_x[g_row * NF + pf0] + pf0 * FD);
      e00 = *(const float4*)&emb[gi * 64 + g_c8];
      e01 = *(const float4*)&emb[gi * 64 + g_c8 + 4];
    }
    if (pre1) {
      long gi = (long)((int)s_x[g_row * NF + pf1] + pf1 * FD);
      e10 = *(const float4*)&emb[gi * 64 + g_c8];
      e11 = *(const float4*)&emb[gi * 64 + g_c8 + 4];
    }

    // compute both fields of the current pair (sequential f0 then f1:
    // preserves round-0 accumulation order exactly)
    #pragma unroll
    for (int ff = 0; ff < 2; ++ff) {
      if (ff == 1 && !hasf1) break;
      const int f = f0 + ff;
      bf16x8 a0 = *(const bf16x8*)&s_emb[cur][ff][(mt * 16 + c16) * 72 + quad * 8];
      bf16x8 a1 = *(const bf16x8*)&s_emb[cur][ff][(mt * 16 + c16) * 72 + 32 + quad * 8];
      #pragma unroll
      for (int j = 0; j < 2; ++j) {
        int row = (nh * 2 + j) * 16 + c16;
        int pc0 = quad ^ (row & 7);
        int pc1 = (quad + 4) ^ (row & 7);
        bf16x8 bb0 = *(const bf16x8*)&s_wt[cur][ff][row * 64 + pc0 * 8];
        bf16x8 bb1 = *(const bf16x8*)&s_wt[cur][ff][row * 64 + pc1 * 8];
        f32x4 acc = {0.f, 0.f, 0.f, 0.f};
        acc = __builtin_amdgcn_mfma_f32_16x16x32_bf16(a0, bb0, acc, 0, 0, 0);
        acc = __builtin_amdgcn_mfma_f32_16x16x32_bf16(a1, bb1, acc, 0, 0, 0);
        float btv = s_bt[f * 64 + row];
        #pragma unroll
        for (int r = 0; r < 4; ++r) {
          float t = acc[r] + btv;
          accS[j][r] += t;
          q[r] += t * t;
        }
      }
    }

    // pack the prefetched pair
    if (pre0) EMB_PACK(nxt, 0, pf0, e00, e01);
    if (pre1) EMB_PACK(nxt, 1, pf1, e10, e11);
    __syncthreads();
  }
#undef EMB_PACK

  // FM: per row r, (S_half0)^2+(S_half1)^2 - q, reduced over the 16 col-lanes
  #pragma unroll
  for (int r = 0; r < 4; ++r) {
    float v = accS[0][r] * accS[0][r] + accS[1][r] * accS[1][r] - q[r];
    v += __shfl_xor(v, 1, 64);
    v += __shfl_xor(v, 2, 64);
    v += __shfl_xor(v, 4, 64);
    v += __shfl_xor(v, 8, 64);
    if (c16 == 0) s_fm[nh * 32 + mt * 16 + quad * 4 + r] = v;
  }
  // first-order term: 8 threads per row, fields strided by 8
  {
    int row = tid >> 3, fi = tid & 7;
    float lv = 0.f;
    for (int f = fi; f < NF; f += 8)
      lv += lin_table[(int)s_x[row * NF + f] + f * FD];
    lv += __shfl_xor(lv, 1, 64);
    lv += __shfl_xor(lv, 2, 64);
    lv += __shfl_xor(lv, 4, 64);
    if (fi == 0) s_lin[row] = lv;
  }
  __syncthreads();
  if (tid < 32)
    base[b0 + tid] = s_lin[tid] + lin_bias[0]
                   + 0.5f * (s_fm[tid] + s_fm[32 + tid]);
}

// ---------------------------------------------------------------------------
// MLP GEMM, m97-style: global_load_lds(16B) staging, XOR-swizzled unpadded
// LDS, tile 128x112xBK64 (4 n-blocks), grid 512 = 2 blocks/CU exactly.
// C = relu((A@B + b)*BN_INV*g + be); cols >=400 written 0.
// ---------------------------------------------------------------------------
__global__ __launch_bounds__(256) void k_gemm(
    const u16* __restrict__ A, int lda, const u16* __restrict__ Bt, int ldb,
    int kit, const float* __restrict__ bias, const float* __restrict__ g,
    const float* __restrict__ be, u16* __restrict__ C, int ldc)
{
  __shared__ __align__(16) u16 sA[128 * 64];  // 16 KB, chunk-swizzled
  __shared__ __align__(16) u16 sB[112 * 64];  // 14 KB

  const int tid = threadIdx.x;
  // 512 blocks = 8 xcd * 16 m * 4 n : co-locate an A-panel's 4 n-blocks per XCD
  int bid = blockIdx.x;
  int xcd = bid & 7;
  int j = bid >> 3;
  const int m0 = (xcd * 16 + (j >> 2)) * 128;
  const int n0 = (j & 3) * 112;

  const int wave = tid >> 6, lane = tid & 63;
  const int quad = lane >> 4, c16 = lane & 15;

  const int srow = lane >> 3;
  const int sclog = (lane & 7) ^ (srow & 7);
  const u16* gA = A + (long)m0 * lda + sclog * 8;
  const u16* gB = Bt + (long)n0 * ldb + sclog * 8;

  f32x4 acc[2][7];
  #pragma unroll
  for (int mtt = 0; mtt < 2; ++mtt)
    #pragma unroll
    for (int nt = 0; nt < 7; ++nt) acc[mtt][nt] = {0.f, 0.f, 0.f, 0.f};

  for (int kk = 0; kk < kit; ++kk) {
    const int k0 = kk * 64;
    #pragma unroll
    for (int it = 0; it < 4; ++it) {
      int s = wave * 4 + it;
      gld16(gA + (long)(s * 8 + srow) * lda + k0, &sA[s * 512]);
    }
    gld16(gB + (long)(wave * 8 + srow) * ldb + k0, &sB[wave * 512]);
    gld16(gB + (long)((wave + 4) * 8 + srow) * ldb + k0, &sB[(wave + 4) * 512]);
    gld16(gB + (long)((wave + 8) * 8 + srow) * ldb + k0, &sB[(wave + 8) * 512]);
    if (wave < 2)
      gld16(gB + (long)((wave + 12) * 8 + srow) * ldb + k0, &sB[(wave + 12) * 512]);
    __syncthreads();

    #pragma unroll
    for (int ks = 0; ks < 2; ++ks) {
      const int co = ((ks * 4 + quad) ^ (c16 & 7)) * 8;
      bf16x8 a0 = *(const bf16x8*)&sA[(wave * 32 + c16) * 64 + co];
      bf16x8 a1 = *(const bf16x8*)&sA[(wave * 32 + 16 + c16) * 64 + co];
      #pragma unroll
      for (int nt = 0; nt < 7; ++nt) {
        bf16x8 b = *(const bf16x8*)&sB[(nt * 16 + c16) * 64 + co];
        acc[0][nt] = __builtin_amdgcn_mfma_f32_16x16x32_bf16(a0, b, acc[0][nt], 0, 0, 0);
        acc[1][nt] = __builtin_amdgcn_mfma_f32_16x16x32_bf16(a1, b, acc[1][nt], 0, 0, 0);
      }
    }
    __syncthreads();
  }

  const float BN_INV = 0.9999950000374997f;
  #pragma unroll
  for (int nt = 0; nt < 7; ++nt) {
    int col = n0 + nt * 16 + c16;
    if (col < 400) {
      float bb = bias[col];
      float sc = BN_INV * g[col];
      float bv = be[col];
      #pragma unroll
      for (int mtt = 0; mtt < 2; ++mtt) {
        #pragma unroll
        for (int r = 0; r < 4; ++r) {
          int row = m0 + wave * 32 + mtt * 16 + quad * 4 + r;
          float y = (acc[mtt][nt][r] + bb) * sc + bv;
          y = fmaxf(y, 0.f);
          C[(long)row * ldc + col] = f2bf(y);
        }
      }
    } else if (col < ldc) {
      #pragma unroll
      for (int mtt = 0; mtt < 2; ++mtt)
        #pragma unroll
        for (int r = 0; r < 4; ++r)
          C[(long)(m0 + wave * 32 + mtt * 16 + quad * 4 + r) * ldc + col] = 0;
    }
  }
}

// ---------------------------------------------------------------------------
// Final: out[b] = sigmoid(base[b] + h3[b,:].Wout + bout). One wave per row.
// ---------------------------------------------------------------------------
__global__ __launch_bounds__(256) void k_final(
    const u16* __restrict__ h3, const float* __restrict__ Wout,
    const float* __restrict__ bout, const float* __restrict__ base,
    float* __restrict__ out)
{
  int wave = threadIdx.x >> 6, lane = threadIdx.x & 63;
  int b = blockIdx.x * 4 + wave;
  float s = 0.f;
  for (int jj = lane; jj < 400; jj += 64)
    s += bf2f(h3[(long)b * 448 + jj]) * Wout[jj];
  #pragma unroll
  for (int m = 32; m >= 1; m >>= 1) s += __shfl_xor(s, m, 64);
  if (lane == 0) {
    float z = s + base[b] + bout[0];
    out[b] = 1.0f / (1.0f + __expf(-z));
  }
}

extern "C" void kernel_launch(void* const* d_in, const int* in_sizes, int n_in,
                              void* d_out, int out_size, void* d_ws, size_t ws_size,
                              hipStream_t stream)
{
  const int*   x         = (const int*)d_in[0];
  const float* emb       = (const float*)d_in[1];
  const float* lin_table = (const float*)d_in[2];
  const float* lin_bias  = (const float*)d_in[3];
  const float* svar      = (const float*)d_in[4];
  const float* Wt        = (const float*)d_in[5];
  const float* bt        = (const float*)d_in[6];
  const float* W1  = (const float*)d_in[7];
  const float* b1  = (const float*)d_in[8];
  const float* g1  = (const float*)d_in[9];
  const float* be1 = (const float*)d_in[10];
  const float* W2  = (const float*)d_in[11];
  const float* b2  = (const float*)d_in[12];
  const float* g2  = (const float*)d_in[13];
  const float* be2 = (const float*)d_in[14];
  const float* W3  = (const float*)d_in[15];
  const float* b3  = (const float*)d_in[16];
  const float* g3  = (const float*)d_in[17];
  const float* be3 = (const float*)d_in[18];
  const float* Wo  = (const float*)d_in[19];
  const float* bo  = (const float*)d_in[20];

  char* ws = (char*)d_ws;
  size_t off = 0;
  u16* h0 = (u16*)(ws + off);     off += (size_t)BT * 2496 * 2;   // 81.8 MB
  u16* h1 = (u16*)(ws + off);     off += (size_t)BT * 448 * 2;
  u16* h2 = (u16*)(ws + off);     off += (size_t)BT * 448 * 2;
  u16* h3 = (u16*)(ws + off);     off += (size_t)BT * 448 * 2;
  float* base = (float*)(ws + off); off += (size_t)BT * 4;
  u16* W1T = (u16*)(ws + off);    off += (size_t)448 * 2496 * 2;
  u16* W2T = (u16*)(ws + off);    off += (size_t)448 * 448 * 2;
  u16* W3T = (u16*)(ws + off);    off += (size_t)448 * 448 * 2;
  u16* Wtb = (u16*)(ws + off);    off += (size_t)NF * 4096 * 2;
  (void)ws_size; (void)in_sizes; (void)n_in; (void)out_size;

  k_prep<<<dim3(14, 78, 4), 256, 0, stream>>>(W1, W1T, W2, W2T, W3, W3T, Wt, Wtb);
  k_embed<<<512, 256, 0, stream>>>(x, emb, lin_table, lin_bias, svar, Wtb, bt,
                                   h0, base);
  k_gemm<<<512, 256, 0, stream>>>(h0, 2496, W1T, 2496, 39, b1, g1, be1, h1, 448);
  k_gemm<<<512, 256, 0, stream>>>(h1, 448, W2T, 448, 7, b2, g2, be2, h2, 448);
  k_gemm<<<512, 256, 0, stream>>>(h2, 448, W3T, 448, 7, b3, g3, be3, h3, 448);
  k_final<<<4096, 256, 0, stream>>>(h3, Wo, bo, base, (float*)d_out);
}